// Round 1
// baseline (490.063 us; speedup 1.0000x reference)
//
#include <hip/hip_runtime.h>

#define PI_D 3.14159265358979323846

// ---------------------------------------------------------------------------
// In-register 64-point radix-2 DIT FFT. Twiddles from LDS (uniform address ->
// broadcast reads, heavily CSE'd by compiler since offsets are constants).
// twr[k] + i*twi[k] = W^k (W = e^{-2pi i/64} fwd, e^{+2pi i/64} inv).
// ---------------------------------------------------------------------------
__device__ __forceinline__ void fft64_regs(float re[64], float im[64],
                                           const float* twr, const float* twi) {
#pragma unroll
  for (int i = 0; i < 64; ++i) {
    unsigned j = __brev((unsigned)i) >> 26;
    if ((int)j > i) {
      float tr = re[i]; re[i] = re[j]; re[j] = tr;
      float ti = im[i]; im[i] = im[j]; im[j] = ti;
    }
  }
#pragma unroll
  for (int s = 0; s < 6; ++s) {
    const int half = 1 << s;
    const int m = half << 1;
    const int tstep = 32 >> s;  // 64/m
#pragma unroll
    for (int k = 0; k < 64; k += m) {
#pragma unroll
      for (int j = 0; j < half; ++j) {
        const float wr = twr[j * tstep];
        const float wi = twi[j * tstep];
        const int a = k + j, b = k + j + half;
        const float tr = re[b] * wr - im[b] * wi;
        const float ti = re[b] * wi + im[b] * wr;
        re[b] = re[a] - tr; im[b] = im[a] - ti;
        re[a] = re[a] + tr; im[a] = im[a] + ti;
      }
    }
  }
}

// ---------------------------------------------------------------------------
// K0: twiddle tables (fp64-generated) + frequency-band indices from fbs.
// tw[0..63]=cos fwd, [64..127]=sin fwd(-), [128..191]=cos inv, [192..255]=sin inv(+)
// idx[0..63]=s_idx, idx[64..127]=e_idx
// ---------------------------------------------------------------------------
__global__ void k_setup(const float* __restrict__ fbs, float* __restrict__ tw,
                        int* __restrict__ idx) {
  const int t = threadIdx.x;  // 64 threads
  double ang = -2.0 * PI_D * (double)t / 64.0;
  tw[t]       = (float)cos(ang);
  tw[64 + t]  = (float)sin(ang);
  tw[128 + t] = (float)cos(ang);
  tw[192 + t] = (float)(-sin(ang));
  // fbs layout [O=1][I=64][2]
  idx[t]      = (int)floorf((fbs[2 * t]     + 1.0f) * 0.5f * 64.0f);
  idx[64 + t] = (int)floorf((fbs[2 * t + 1] + 1.0f) * 0.5f * 64.0f);
}

// ---------------------------------------------------------------------------
// K1: forward FFT2 per (b,i) image. One wave per image. F layout [b][i][u][v].
// ---------------------------------------------------------------------------
__global__ __launch_bounds__(64) void k_fft_fwd(const float* __restrict__ x,
                                                float2* __restrict__ F,
                                                const float* __restrict__ twg) {
  __shared__ float lre[64][68];  // 68 pad: 16B-aligned rows, (4k+t)%32 -> 2-way only
  __shared__ float lim[64][68];
  __shared__ float twr[64], twi[64];
  const int t = threadIdx.x;
  const int img = blockIdx.x;
  twr[t] = twg[t];
  twi[t] = twg[64 + t];
  const float* xp = x + ((size_t)img << 12);
#pragma unroll
  for (int k = 0; k < 64; ++k) lre[k][t] = xp[k * 64 + t];  // coalesced
  __syncthreads();
  {  // row FFTs: thread t owns row t (real input)
    float re[64], im[64];
#pragma unroll
    for (int j = 0; j < 64; ++j) { re[j] = lre[t][j]; im[j] = 0.0f; }
    fft64_regs(re, im, twr, twi);
#pragma unroll
    for (int j = 0; j < 64; ++j) { lre[t][j] = re[j]; lim[t][j] = im[j]; }
  }
  __syncthreads();
  {  // column FFTs: thread t owns column t
    float re[64], im[64];
#pragma unroll
    for (int j = 0; j < 64; ++j) { re[j] = lre[j][t]; im[j] = lim[j][t]; }
    fft64_regs(re, im, twr, twi);
#pragma unroll
    for (int j = 0; j < 64; ++j) { lre[j][t] = re[j]; lim[j][t] = im[j]; }
  }
  __syncthreads();
  float2* Fp = F + ((size_t)img << 12);
#pragma unroll
  for (int k = 0; k < 64; ++k)
    Fp[k * 64 + t] = make_float2(lre[k][t], lim[k][t]);  // coalesced dwordx2
}

// ---------------------------------------------------------------------------
// K2: attention (two 1x1 convs + softmax over 3 scales) fused with log-Gabor
// filter evaluation -> Wc[i][h][w] = sum_s filters[s,i,h,w]*aw[i,s,h,w].
// Thread = one (i,h,w) position in shifted space; m[64] spectrum magnitudes in
// VGPRs; w1/w2/b1/b2 reads are wave-uniform -> scalar loads.
// ---------------------------------------------------------------------------
__global__ __launch_bounds__(256) void k_attn(
    const float2* __restrict__ F, const float* __restrict__ w1,
    const float* __restrict__ b1, const float* __restrict__ w2,
    const float* __restrict__ b2, const float* __restrict__ f0,
    const float* __restrict__ theta, const float* __restrict__ sigma,
    const float* __restrict__ theta0, float* __restrict__ Wc) {
  const int i = blockIdx.x >> 4;                       // shifted-space batch==channel
  const int pos = ((blockIdx.x & 15) << 8) + threadIdx.x;
  const int h = pos >> 6, w = pos & 63;
  const int b_f = (i + 32) & 63;
  const int u_f = (h + 32) & 63;
  const int v_f = (w + 32) & 63;
  const float2* Fb = F + ((size_t)b_f << 18);
  float m[64];
#pragma unroll 8
  for (int c = 0; c < 64; ++c) {
    const int c_f = (c + 32) & 63;
    float2 v = Fb[((size_t)c_f << 12) + (u_f << 6) + v_f];
    m[c] = sqrtf(v.x * v.x + v.y * v.y);
  }
  float l0 = b2[0], l1 = b2[1], l2 = b2[2];
#pragma unroll 4
  for (int k = 0; k < 64; ++k) {
    float acc = b1[k];
#pragma unroll
    for (int c = 0; c < 64; ++c) acc = fmaf(w1[(k << 6) + c], m[c], acc);
    float hv = fmaxf(acc, 0.0f);
    l0 = fmaf(w2[k], hv, l0);          // w2 layout [S=3][HID=64]
    l1 = fmaf(w2[64 + k], hv, l1);
    l2 = fmaf(w2[128 + k], hv, l2);
  }
  float mx = fmaxf(l0, fmaxf(l1, l2));
  float e0 = expf(l0 - mx), e1 = expf(l1 - mx), e2 = expf(l2 - mx);
  float inv = 1.0f / (e0 + e1 + e2);
  float aw0 = e0 * inv, aw1 = e1 * inv, aw2 = e2 * inv;
  // log-Gabor filters on the raw (h,w) grid
  const float yy = -1.0f + (float)h * (2.0f / 63.0f);
  const float xx = -1.0f + (float)w * (2.0f / 63.0f);
  const float r = sqrtf(xx * xx + yy * yy + 1e-6f);
  const float lr = logf(r);
  const float phi = atan2f(yy, xx);
  float wc = 0.0f;
  const float aws[3] = {aw0, aw1, aw2};
#pragma unroll
  for (int s = 0; s < 3; ++s) {
    const float f0v = f0[s * 64 + i];       // [S][O=1][I]
    const float sgv = sigma[s * 64 + i];
    const float thv = theta[s * 64 + i];
    const float t0v = theta0[s * 64 + i];
    const float ls = logf(sgv);
    const float d1 = lr - logf(f0v);
    const float g1 = expf(-(d1 * d1) / (2.0f * ls * ls));
    const float d2 = phi - thv;
    const float g2 = expf(-(d2 * d2) / (2.0f * t0v * t0v));
    wc = fmaf(g1 * g2, aws[s], wc);
  }
  Wc[((i << 6) + h) * 64 + w] = wc;
}

// ---------------------------------------------------------------------------
// K3: spatial 3x3 conv, out channels = 1. Block = (b, 4-row strip), all 64
// input channels' 6-row slabs staged in LDS (96 KB).
// ---------------------------------------------------------------------------
__global__ __launch_bounds__(256) void k_conv(const float* __restrict__ x,
                                              const float* __restrict__ cw,
                                              float* __restrict__ xsp) {
  __shared__ float tile[64][6][64];  // [ch][row][w], 96 KB
  __shared__ float wsm[576];
  const int b = blockIdx.x >> 4;
  const int strip = blockIdx.x & 15;
  const int h0 = strip << 2;
  const int t = threadIdx.x;
  for (int q = t; q < 576; q += 256) wsm[q] = cw[q];
  for (int q = t; q < 64 * 6 * 64; q += 256) {
    const int w = q & 63;
    const int r = (q >> 6) % 6;
    const int ch = q / 384;
    const int hh = h0 - 1 + r;
    tile[ch][r][w] =
        (hh >= 0 && hh < 64) ? x[(((size_t)b << 6) + ch) * 4096 + hh * 64 + w] : 0.0f;
  }
  __syncthreads();
  const int w = t & 63;
  const int hr = t >> 6;  // output row h0+hr uses tile rows hr..hr+2
  float acc = 0.0f;
  for (int ch = 0; ch < 64; ++ch) {
    const float* wp = &wsm[ch * 9];
    const float* rm = tile[ch][hr];
    const float* r0 = tile[ch][hr + 1];
    const float* rp = tile[ch][hr + 2];
    if (w > 0) {
      acc = fmaf(rm[w - 1], wp[0], acc);
      acc = fmaf(r0[w - 1], wp[3], acc);
      acc = fmaf(rp[w - 1], wp[6], acc);
    }
    acc = fmaf(rm[w], wp[1], acc);
    acc = fmaf(r0[w], wp[4], acc);
    acc = fmaf(rp[w], wp[7], acc);
    if (w < 63) {
      acc = fmaf(rm[w + 1], wp[2], acc);
      acc = fmaf(r0[w + 1], wp[5], acc);
      acc = fmaf(rp[w + 1], wp[8], acc);
    }
  }
  xsp[((size_t)b << 12) + (h0 + hr) * 64 + w] = acc;
}

// ---------------------------------------------------------------------------
// K4: G[b,i,u,v] = F[b,i,u,v]*Wc[i+,u+,v+]*mask(b+,i+,u+); IFFT2; real part;
// mix with conv path. Images with chanmask==0 skip the IFFT entirely.
// ---------------------------------------------------------------------------
__global__ __launch_bounds__(64) void k_ifft_out(
    const float2* __restrict__ F, const float* __restrict__ Wc,
    const float* __restrict__ xsp, const int* __restrict__ idx,
    const float* __restrict__ mixp, float* __restrict__ out,
    const float* __restrict__ twg) {
  __shared__ float lre[64][68];
  __shared__ float lim[64][68];
  __shared__ float twr[64], twi[64];
  const int t = threadIdx.x;
  const int img = blockIdx.x;
  const int b = img >> 6, i = img & 63;
  const int b_s = (b + 32) & 63, i_s = (i + 32) & 63;
  const int s0 = idx[b_s], e0 = idx[64 + b_s];
  const float mixv = mixp[0];
  float* op = out + ((size_t)img << 12);
  const float* xp = xsp + ((size_t)b << 12);
  if (!((i_s >= s0) && (i_s < e0))) {  // block-uniform: x_filtered == 0
    const float om = 1.0f - mixv;
#pragma unroll
    for (int k = 0; k < 64; ++k) op[k * 64 + t] = om * xp[k * 64 + t];
    return;
  }
  twr[t] = twg[128 + t];
  twi[t] = twg[192 + t];
  const float2* Fp = F + ((size_t)img << 12);
  const float* Wcp = Wc + ((size_t)i_s << 12);
  const int v_s = (t + 32) & 63;
#pragma unroll
  for (int k = 0; k < 64; ++k) {
    const int u_s = (k + 32) & 63;
    float wv = 0.0f;
    if (u_s >= s0 && u_s < e0) wv = Wcp[(u_s << 6) + v_s];
    float2 f = Fp[k * 64 + t];
    lre[k][t] = f.x * wv;
    lim[k][t] = f.y * wv;
  }
  __syncthreads();
  {  // row inverse FFTs
    float re[64], im[64];
#pragma unroll
    for (int j = 0; j < 64; ++j) { re[j] = lre[t][j]; im[j] = lim[t][j]; }
    fft64_regs(re, im, twr, twi);
#pragma unroll
    for (int j = 0; j < 64; ++j) { lre[t][j] = re[j]; lim[t][j] = im[j]; }
  }
  __syncthreads();
  {  // column inverse FFTs
    float re[64], im[64];
#pragma unroll
    for (int j = 0; j < 64; ++j) { re[j] = lre[j][t]; im[j] = lim[j][t]; }
    fft64_regs(re, im, twr, twi);
#pragma unroll
    for (int j = 0; j < 64; ++j) { lre[j][t] = re[j]; lim[j][t] = im[j]; }
  }
  __syncthreads();
  const float sc = mixv * (1.0f / 4096.0f);
  const float om = 1.0f - mixv;
#pragma unroll
  for (int k = 0; k < 64; ++k)
    op[k * 64 + t] = fmaf(sc, lre[k][t], om * xp[k * 64 + t]);
}

// ---------------------------------------------------------------------------
// Workspace layout (needs ~136.3 MB):
//   [0, 128MB)              F        float2[4096*4096]
//   [+0MB, +1MB)            Wc       float[64*64*64]
//   [+1MB, +2MB)            xsp      float[64*64*64]
//   [+2MB, +2MB+1KB)        tw       float[256]
//   [+2MB+1KB, ...)         idx      int[128]
// ---------------------------------------------------------------------------
extern "C" void kernel_launch(void* const* d_in, const int* in_sizes, int n_in,
                              void* d_out, int out_size, void* d_ws, size_t ws_size,
                              hipStream_t stream) {
  const float* x      = (const float*)d_in[0];
  const float* f0     = (const float*)d_in[1];
  const float* theta  = (const float*)d_in[2];
  const float* sigma  = (const float*)d_in[3];
  const float* theta0 = (const float*)d_in[4];
  const float* fbs    = (const float*)d_in[5];
  const float* mix    = (const float*)d_in[6];
  const float* w1     = (const float*)d_in[7];
  const float* b1     = (const float*)d_in[8];
  const float* w2     = (const float*)d_in[9];
  const float* b2     = (const float*)d_in[10];
  const float* cw     = (const float*)d_in[11];
  float* out = (float*)d_out;
  char* ws = (char*)d_ws;
  float2* F  = (float2*)(ws);
  float* Wc  = (float*)(ws + 134217728);
  float* xsp = (float*)(ws + 134217728 + 1048576);
  float* tw  = (float*)(ws + 134217728 + 2097152);
  int* idx   = (int*)(ws + 134217728 + 2097152 + 1024);

  k_setup<<<1, 64, 0, stream>>>(fbs, tw, idx);
  k_fft_fwd<<<4096, 64, 0, stream>>>(x, F, tw);
  k_attn<<<1024, 256, 0, stream>>>(F, w1, b1, w2, b2, f0, theta, sigma, theta0, Wc);
  k_conv<<<1024, 256, 0, stream>>>(x, cw, xsp);
  k_ifft_out<<<4096, 64, 0, stream>>>(F, Wc, xsp, idx, mix, out, tw);
}

// Round 2
// 311.275 us; speedup vs baseline: 1.5744x; 1.5744x over previous
//
#include <hip/hip_runtime.h>

#define PI_D 3.14159265358979323846

// ---------------------------------------------------------------------------
// In-register 64-point radix-2 DIT FFT. Twiddles from LDS (uniform address ->
// broadcast reads, heavily CSE'd by compiler since offsets are constants).
// twr[k] + i*twi[k] = W^k (W = e^{-2pi i/64} fwd, e^{+2pi i/64} inv).
// ---------------------------------------------------------------------------
__device__ __forceinline__ void fft64_regs(float re[64], float im[64],
                                           const float* twr, const float* twi) {
#pragma unroll
  for (int i = 0; i < 64; ++i) {
    unsigned j = __brev((unsigned)i) >> 26;
    if ((int)j > i) {
      float tr = re[i]; re[i] = re[j]; re[j] = tr;
      float ti = im[i]; im[i] = im[j]; im[j] = ti;
    }
  }
#pragma unroll
  for (int s = 0; s < 6; ++s) {
    const int half = 1 << s;
    const int m = half << 1;
    const int tstep = 32 >> s;  // 64/m
#pragma unroll
    for (int k = 0; k < 64; k += m) {
#pragma unroll
      for (int j = 0; j < half; ++j) {
        const float wr = twr[j * tstep];
        const float wi = twi[j * tstep];
        const int a = k + j, b = k + j + half;
        const float tr = re[b] * wr - im[b] * wi;
        const float ti = re[b] * wi + im[b] * wr;
        re[b] = re[a] - tr; im[b] = im[a] - ti;
        re[a] = re[a] + tr; im[a] = im[a] + ti;
      }
    }
  }
}

// ---------------------------------------------------------------------------
// K0: twiddle tables (fp64-generated) + frequency-band indices from fbs.
// tw[0..63]=cos fwd, [64..127]=sin fwd(-), [128..191]=cos inv, [192..255]=sin inv(+)
// idx[0..63]=s_idx, idx[64..127]=e_idx
// ---------------------------------------------------------------------------
__global__ void k_setup(const float* __restrict__ fbs, float* __restrict__ tw,
                        int* __restrict__ idx) {
  const int t = threadIdx.x;  // 64 threads
  double ang = -2.0 * PI_D * (double)t / 64.0;
  tw[t]       = (float)cos(ang);
  tw[64 + t]  = (float)sin(ang);
  tw[128 + t] = (float)cos(ang);
  tw[192 + t] = (float)(-sin(ang));
  // fbs layout [O=1][I=64][2]
  idx[t]      = (int)floorf((fbs[2 * t]     + 1.0f) * 0.5f * 64.0f);
  idx[64 + t] = (int)floorf((fbs[2 * t + 1] + 1.0f) * 0.5f * 64.0f);
}

// ---------------------------------------------------------------------------
// K1: forward FFT2 per (b,i) image. One wave per image. F layout [b][i][u][v].
// ---------------------------------------------------------------------------
__global__ __launch_bounds__(64) void k_fft_fwd(const float* __restrict__ x,
                                                float2* __restrict__ F,
                                                const float* __restrict__ twg) {
  __shared__ float lre[64][68];  // 68 pad: 16B-aligned rows, (4k+t)%32 -> 2-way only
  __shared__ float lim[64][68];
  __shared__ float twr[64], twi[64];
  const int t = threadIdx.x;
  const int img = blockIdx.x;
  twr[t] = twg[t];
  twi[t] = twg[64 + t];
  const float* xp = x + ((size_t)img << 12);
#pragma unroll
  for (int k = 0; k < 64; ++k) lre[k][t] = xp[k * 64 + t];  // coalesced
  __syncthreads();
  {  // row FFTs: thread t owns row t (real input)
    float re[64], im[64];
#pragma unroll
    for (int j = 0; j < 64; ++j) { re[j] = lre[t][j]; im[j] = 0.0f; }
    fft64_regs(re, im, twr, twi);
#pragma unroll
    for (int j = 0; j < 64; ++j) { lre[t][j] = re[j]; lim[t][j] = im[j]; }
  }
  __syncthreads();
  {  // column FFTs: thread t owns column t
    float re[64], im[64];
#pragma unroll
    for (int j = 0; j < 64; ++j) { re[j] = lre[j][t]; im[j] = lim[j][t]; }
    fft64_regs(re, im, twr, twi);
#pragma unroll
    for (int j = 0; j < 64; ++j) { lre[j][t] = re[j]; lim[j][t] = im[j]; }
  }
  __syncthreads();
  float2* Fp = F + ((size_t)img << 12);
#pragma unroll
  for (int k = 0; k < 64; ++k)
    Fp[k * 64 + t] = make_float2(lre[k][t], lim[k][t]);  // coalesced dwordx2
}

// ---------------------------------------------------------------------------
// K2: attention (two 1x1 convs + softmax over 3 scales) fused with log-Gabor
// filter evaluation -> Wc[i][h][w] = sum_s filters[s,i,h,w]*aw[i,s,h,w].
// Thread = one (i,h,w) position in shifted space; m[64] spectrum magnitudes in
// VGPRs; w1/w2/b1/b2 reads are wave-uniform -> scalar loads.
// ---------------------------------------------------------------------------
__global__ __launch_bounds__(256) void k_attn(
    const float2* __restrict__ F, const float* __restrict__ w1,
    const float* __restrict__ b1, const float* __restrict__ w2,
    const float* __restrict__ b2, const float* __restrict__ f0,
    const float* __restrict__ theta, const float* __restrict__ sigma,
    const float* __restrict__ theta0, float* __restrict__ Wc) {
  const int i = blockIdx.x >> 4;                       // shifted-space batch==channel
  const int pos = ((blockIdx.x & 15) << 8) + threadIdx.x;
  const int h = pos >> 6, w = pos & 63;
  const int b_f = (i + 32) & 63;
  const int u_f = (h + 32) & 63;
  const int v_f = (w + 32) & 63;
  const float2* Fb = F + ((size_t)b_f << 18);
  float m[64];
#pragma unroll 8
  for (int c = 0; c < 64; ++c) {
    const int c_f = (c + 32) & 63;
    float2 v = Fb[((size_t)c_f << 12) + (u_f << 6) + v_f];
    m[c] = sqrtf(v.x * v.x + v.y * v.y);
  }
  float l0 = b2[0], l1 = b2[1], l2 = b2[2];
#pragma unroll 4
  for (int k = 0; k < 64; ++k) {
    float acc = b1[k];
#pragma unroll
    for (int c = 0; c < 64; ++c) acc = fmaf(w1[(k << 6) + c], m[c], acc);
    float hv = fmaxf(acc, 0.0f);
    l0 = fmaf(w2[k], hv, l0);          // w2 layout [S=3][HID=64]
    l1 = fmaf(w2[64 + k], hv, l1);
    l2 = fmaf(w2[128 + k], hv, l2);
  }
  float mx = fmaxf(l0, fmaxf(l1, l2));
  float e0 = expf(l0 - mx), e1 = expf(l1 - mx), e2 = expf(l2 - mx);
  float inv = 1.0f / (e0 + e1 + e2);
  float aw0 = e0 * inv, aw1 = e1 * inv, aw2 = e2 * inv;
  // log-Gabor filters on the raw (h,w) grid
  const float yy = -1.0f + (float)h * (2.0f / 63.0f);
  const float xx = -1.0f + (float)w * (2.0f / 63.0f);
  const float r = sqrtf(xx * xx + yy * yy + 1e-6f);
  const float lr = logf(r);
  const float phi = atan2f(yy, xx);
  float wc = 0.0f;
  const float aws[3] = {aw0, aw1, aw2};
#pragma unroll
  for (int s = 0; s < 3; ++s) {
    const float f0v = f0[s * 64 + i];       // [S][O=1][I]
    const float sgv = sigma[s * 64 + i];
    const float thv = theta[s * 64 + i];
    const float t0v = theta0[s * 64 + i];
    const float ls = logf(sgv);
    const float d1 = lr - logf(f0v);
    const float g1 = expf(-(d1 * d1) / (2.0f * ls * ls));
    const float d2 = phi - thv;
    const float g2 = expf(-(d2 * d2) / (2.0f * t0v * t0v));
    wc = fmaf(g1 * g2, aws[s], wc);
  }
  Wc[((i << 6) + h) * 64 + w] = wc;
}

// ---------------------------------------------------------------------------
// K3 v2: spatial 3x3 conv, Cout=1. One WAVE per output row (b,row); lane = w.
// Per channel: 3 coalesced global loads (rows row-1..row+1 at col=lane) and
// 9 FMAs into P[i][j] = sum_ch x[ch,row-1+i,lane]*cw[ch,i,j]. The w+-1
// neighbor terms are assembled ONCE at the end via 2 lane shuffles (the
// neighbor lane's partial sums), with all boundary masks folded in the
// epilogue. No big LDS tile -> 16 waves/CU instead of 4; ~192 loads+576 FMA
// per wave. // block=256: 4 waves = 4 consecutive rows -> L1 row reuse (3x).
// ---------------------------------------------------------------------------
__global__ __launch_bounds__(256) void k_conv(const float* __restrict__ x,
                                              const float* __restrict__ cw,
                                              float* __restrict__ xsp) {
  __shared__ float wsm[576];
  const int t = threadIdx.x;
  for (int q = t; q < 576; q += 256) wsm[q] = cw[q];
  __syncthreads();
  const int lane = t & 63;
  const int wv = t >> 6;
  const int b = blockIdx.x >> 4;
  const int row = ((blockIdx.x & 15) << 2) | wv;
  const float* xb = x + ((size_t)b << 18);
  const int rm = row > 0 ? row - 1 : 0;    // clamped (masked in epilogue)
  const int rp = row < 63 ? row + 1 : 63;
  float P00 = 0.f, P01 = 0.f, P02 = 0.f;
  float P10 = 0.f, P11 = 0.f, P12 = 0.f;
  float P20 = 0.f, P21 = 0.f, P22 = 0.f;
#pragma unroll 4
  for (int ch = 0; ch < 64; ++ch) {
    const float* xc = xb + (ch << 12);
    const float v0 = xc[(rm << 6) + lane];
    const float v1 = xc[(row << 6) + lane];
    const float v2 = xc[(rp << 6) + lane];
    const float* wp = &wsm[ch * 9];
    P00 = fmaf(v0, wp[0], P00);
    P01 = fmaf(v0, wp[1], P01);
    P02 = fmaf(v0, wp[2], P02);
    P10 = fmaf(v1, wp[3], P10);
    P11 = fmaf(v1, wp[4], P11);
    P12 = fmaf(v1, wp[5], P12);
    P20 = fmaf(v2, wp[6], P20);
    P21 = fmaf(v2, wp[7], P21);
    P22 = fmaf(v2, wp[8], P22);
  }
  // Fold row-validity masks (wave-uniform) then assemble w+-1 via shuffles.
  const float tmask = (row > 0) ? 1.0f : 0.0f;
  const float bmask = (row < 63) ? 1.0f : 0.0f;
  const float Ql = tmask * P00 + P10 + bmask * P20;  // this lane's x * w[i][0]
  const float Qm = tmask * P01 + P11 + bmask * P21;
  const float Qr = tmask * P02 + P12 + bmask * P22;
  // out(w) needs Ql from lane w-1 (term x[w-1]*w[i][0]) and Qr from lane w+1.
  const float fromL = __shfl_up(Ql, 1, 64);
  const float fromR = __shfl_down(Qr, 1, 64);
  float acc = Qm;
  if (lane > 0) acc += fromL;
  if (lane < 63) acc += fromR;
  xsp[((size_t)b << 12) + (row << 6) + lane] = acc;
}

// ---------------------------------------------------------------------------
// K4: G[b,i,u,v] = F[b,i,u,v]*Wc[i+,u+,v+]*mask(b+,i+,u+); IFFT2; real part;
// mix with conv path. Images with chanmask==0 skip the IFFT entirely.
// ---------------------------------------------------------------------------
__global__ __launch_bounds__(64) void k_ifft_out(
    const float2* __restrict__ F, const float* __restrict__ Wc,
    const float* __restrict__ xsp, const int* __restrict__ idx,
    const float* __restrict__ mixp, float* __restrict__ out,
    const float* __restrict__ twg) {
  __shared__ float lre[64][68];
  __shared__ float lim[64][68];
  __shared__ float twr[64], twi[64];
  const int t = threadIdx.x;
  const int img = blockIdx.x;
  const int b = img >> 6, i = img & 63;
  const int b_s = (b + 32) & 63, i_s = (i + 32) & 63;
  const int s0 = idx[b_s], e0 = idx[64 + b_s];
  const float mixv = mixp[0];
  float* op = out + ((size_t)img << 12);
  const float* xp = xsp + ((size_t)b << 12);
  if (!((i_s >= s0) && (i_s < e0))) {  // block-uniform: x_filtered == 0
    const float om = 1.0f - mixv;
#pragma unroll
    for (int k = 0; k < 64; ++k) op[k * 64 + t] = om * xp[k * 64 + t];
    return;
  }
  twr[t] = twg[128 + t];
  twi[t] = twg[192 + t];
  const float2* Fp = F + ((size_t)img << 12);
  const float* Wcp = Wc + ((size_t)i_s << 12);
  const int v_s = (t + 32) & 63;
#pragma unroll
  for (int k = 0; k < 64; ++k) {
    const int u_s = (k + 32) & 63;
    float wv = 0.0f;
    if (u_s >= s0 && u_s < e0) wv = Wcp[(u_s << 6) + v_s];
    float2 f = Fp[k * 64 + t];
    lre[k][t] = f.x * wv;
    lim[k][t] = f.y * wv;
  }
  __syncthreads();
  {  // row inverse FFTs
    float re[64], im[64];
#pragma unroll
    for (int j = 0; j < 64; ++j) { re[j] = lre[t][j]; im[j] = lim[t][j]; }
    fft64_regs(re, im, twr, twi);
#pragma unroll
    for (int j = 0; j < 64; ++j) { lre[t][j] = re[j]; lim[t][j] = im[j]; }
  }
  __syncthreads();
  {  // column inverse FFTs
    float re[64], im[64];
#pragma unroll
    for (int j = 0; j < 64; ++j) { re[j] = lre[j][t]; im[j] = lim[j][t]; }
    fft64_regs(re, im, twr, twi);
#pragma unroll
    for (int j = 0; j < 64; ++j) { lre[j][t] = re[j]; lim[j][t] = im[j]; }
  }
  __syncthreads();
  const float sc = mixv * (1.0f / 4096.0f);
  const float om = 1.0f - mixv;
#pragma unroll
  for (int k = 0; k < 64; ++k)
    op[k * 64 + t] = fmaf(sc, lre[k][t], om * xp[k * 64 + t]);
}

// ---------------------------------------------------------------------------
// Workspace layout (needs ~136.3 MB):
//   [0, 128MB)              F        float2[4096*4096]
//   [+0MB, +1MB)            Wc       float[64*64*64]
//   [+1MB, +2MB)            xsp      float[64*64*64]
//   [+2MB, +2MB+1KB)        tw       float[256]
//   [+2MB+1KB, ...)         idx      int[128]
// ---------------------------------------------------------------------------
extern "C" void kernel_launch(void* const* d_in, const int* in_sizes, int n_in,
                              void* d_out, int out_size, void* d_ws, size_t ws_size,
                              hipStream_t stream) {
  const float* x      = (const float*)d_in[0];
  const float* f0     = (const float*)d_in[1];
  const float* theta  = (const float*)d_in[2];
  const float* sigma  = (const float*)d_in[3];
  const float* theta0 = (const float*)d_in[4];
  const float* fbs    = (const float*)d_in[5];
  const float* mix    = (const float*)d_in[6];
  const float* w1     = (const float*)d_in[7];
  const float* b1     = (const float*)d_in[8];
  const float* w2     = (const float*)d_in[9];
  const float* b2     = (const float*)d_in[10];
  const float* cw     = (const float*)d_in[11];
  float* out = (float*)d_out;
  char* ws = (char*)d_ws;
  float2* F  = (float2*)(ws);
  float* Wc  = (float*)(ws + 134217728);
  float* xsp = (float*)(ws + 134217728 + 1048576);
  float* tw  = (float*)(ws + 134217728 + 2097152);
  int* idx   = (int*)(ws + 134217728 + 2097152 + 1024);

  k_setup<<<1, 64, 0, stream>>>(fbs, tw, idx);
  k_fft_fwd<<<4096, 64, 0, stream>>>(x, F, tw);
  k_attn<<<1024, 256, 0, stream>>>(F, w1, b1, w2, b2, f0, theta, sigma, theta0, Wc);
  k_conv<<<1024, 256, 0, stream>>>(x, cw, xsp);
  k_ifft_out<<<4096, 64, 0, stream>>>(F, Wc, xsp, idx, mix, out, tw);
}

// Round 3
// 289.462 us; speedup vs baseline: 1.6930x; 1.0754x over previous
//
#include <hip/hip_runtime.h>

#define PI_D 3.14159265358979323846

// ---------------------------------------------------------------------------
// In-register 64-point radix-2 DIT FFT. Twiddles from LDS (uniform address ->
// broadcast reads, heavily CSE'd by compiler since offsets are constants).
// twr[k] + i*twi[k] = W^k (W = e^{-2pi i/64} fwd, e^{+2pi i/64} inv).
// ---------------------------------------------------------------------------
__device__ __forceinline__ void fft64_regs(float re[64], float im[64],
                                           const float* twr, const float* twi) {
#pragma unroll
  for (int i = 0; i < 64; ++i) {
    unsigned j = __brev((unsigned)i) >> 26;
    if ((int)j > i) {
      float tr = re[i]; re[i] = re[j]; re[j] = tr;
      float ti = im[i]; im[i] = im[j]; im[j] = ti;
    }
  }
#pragma unroll
  for (int s = 0; s < 6; ++s) {
    const int half = 1 << s;
    const int m = half << 1;
    const int tstep = 32 >> s;  // 64/m
#pragma unroll
    for (int k = 0; k < 64; k += m) {
#pragma unroll
      for (int j = 0; j < half; ++j) {
        const float wr = twr[j * tstep];
        const float wi = twi[j * tstep];
        const int a = k + j, b = k + j + half;
        const float tr = re[b] * wr - im[b] * wi;
        const float ti = re[b] * wi + im[b] * wr;
        re[b] = re[a] - tr; im[b] = im[a] - ti;
        re[a] = re[a] + tr; im[a] = im[a] + ti;
      }
    }
  }
}

// ---------------------------------------------------------------------------
// K0: twiddle tables (fp64-generated) + frequency-band indices from fbs.
// tw[0..63]=cos fwd, [64..127]=sin fwd(-), [128..191]=cos inv, [192..255]=sin inv(+)
// idx[0..63]=s_idx, idx[64..127]=e_idx
// ---------------------------------------------------------------------------
__global__ void k_setup(const float* __restrict__ fbs, float* __restrict__ tw,
                        int* __restrict__ idx) {
  const int t = threadIdx.x;  // 64 threads
  double ang = -2.0 * PI_D * (double)t / 64.0;
  tw[t]       = (float)cos(ang);
  tw[64 + t]  = (float)sin(ang);
  tw[128 + t] = (float)cos(ang);
  tw[192 + t] = (float)(-sin(ang));
  // fbs layout [O=1][I=64][2]
  idx[t]      = (int)floorf((fbs[2 * t]     + 1.0f) * 0.5f * 64.0f);
  idx[64 + t] = (int)floorf((fbs[2 * t + 1] + 1.0f) * 0.5f * 64.0f);
}

// ---------------------------------------------------------------------------
// K1: forward FFT2 per (b,i) image. One wave per image.
// Output: if image (b,i) passes the frequency-band mask ("active", ~8%),
// write full complex F (float2[4096]) into its 32KB slot (k_ifft_out + k_attn
// read it). Otherwise write ONLY |F| (float[4096]) into the same slot --
// k_attn is the only consumer and needs just magnitudes. Saves ~57 MB of
// writes here and ~60 MB of reads in k_attn.
// LDS stride 65: (t+j)%32 bank pattern -> 2-way only (free) on both the
// row-major and column-major phases (68 gave 8-way on row-major writes).
// ---------------------------------------------------------------------------
__global__ __launch_bounds__(64) void k_fft_fwd(const float* __restrict__ x,
                                                float2* __restrict__ F,
                                                const float* __restrict__ twg,
                                                const int* __restrict__ idx) {
  __shared__ float lre[64][65];
  __shared__ float lim[64][65];
  __shared__ float twr[64], twi[64];
  const int t = threadIdx.x;
  const int img = blockIdx.x;
  twr[t] = twg[t];
  twi[t] = twg[64 + t];
  const float* xp = x + ((size_t)img << 12);
#pragma unroll
  for (int k = 0; k < 64; ++k) lre[k][t] = xp[k * 64 + t];  // coalesced
  __syncthreads();
  {  // row FFTs: thread t owns row t (real input)
    float re[64], im[64];
#pragma unroll
    for (int j = 0; j < 64; ++j) { re[j] = lre[t][j]; im[j] = 0.0f; }
    fft64_regs(re, im, twr, twi);
#pragma unroll
    for (int j = 0; j < 64; ++j) { lre[t][j] = re[j]; lim[t][j] = im[j]; }
  }
  __syncthreads();
  {  // column FFTs: thread t owns column t
    float re[64], im[64];
#pragma unroll
    for (int j = 0; j < 64; ++j) { re[j] = lre[j][t]; im[j] = lim[j][t]; }
    fft64_regs(re, im, twr, twi);
#pragma unroll
    for (int j = 0; j < 64; ++j) { lre[j][t] = re[j]; lim[j][t] = im[j]; }
  }
  __syncthreads();
  const int b = img >> 6, i = img & 63;
  const int b_s = (b + 32) & 63, i_s = (i + 32) & 63;
  const int s0 = idx[b_s], e0 = idx[64 + b_s];
  float2* Fp = F + ((size_t)img << 12);
  if ((i_s >= s0) && (i_s < e0)) {  // active: full complex spectrum
#pragma unroll
    for (int k = 0; k < 64; ++k)
      Fp[k * 64 + t] = make_float2(lre[k][t], lim[k][t]);  // coalesced dwordx2
  } else {  // inactive: magnitudes only, packed as float[4096] in the slot
    float* Mp = (float*)Fp;
#pragma unroll
    for (int k = 0; k < 64; ++k) {
      const float re = lre[k][t], im = lim[k][t];
      Mp[k * 64 + t] = sqrtf(re * re + im * im);
    }
  }
}

// ---------------------------------------------------------------------------
// K2: attention (two 1x1 convs + softmax over 3 scales) fused with log-Gabor
// filter evaluation -> Wc[i][h][w] = sum_s filters[s,i,h,w]*aw[i,s,h,w].
// Thread = one (i,h,w) position in shifted space; m[64] spectrum magnitudes
// FULLY unrolled into VGPRs (partial unroll forced a scratch spill: R2 showed
// VGPR=40 + 65MB scratch writes). Per-channel active test is block-uniform:
// in attn coords the active images are exactly c in [idx[i], idx[64+i]).
// Active channels (~8%) read float2 + sqrt; inactive read the packed |F|.
// ---------------------------------------------------------------------------
__global__ __launch_bounds__(256) void k_attn(
    const float2* __restrict__ F, const float* __restrict__ w1,
    const float* __restrict__ b1, const float* __restrict__ w2,
    const float* __restrict__ b2, const float* __restrict__ f0,
    const float* __restrict__ theta, const float* __restrict__ sigma,
    const float* __restrict__ theta0, const int* __restrict__ idx,
    float* __restrict__ Wc) {
  const int i = blockIdx.x >> 4;                       // shifted-space batch==channel
  const int pos = ((blockIdx.x & 15) << 8) + threadIdx.x;
  const int h = pos >> 6, w = pos & 63;
  const int b_f = (i + 32) & 63;
  const int u_f = (h + 32) & 63;
  const int v_f = (w + 32) & 63;
  const int pos_f = (u_f << 6) + v_f;
  const int s0a = idx[i], e0a = idx[64 + i];
  float m[64];
#pragma unroll
  for (int c = 0; c < 64; ++c) {
    const int c_f = (c + 32) & 63;
    const float2* Fimg = F + (((size_t)b_f << 18) + ((size_t)c_f << 12));
    if (c >= s0a && c < e0a) {  // block-uniform branch
      float2 v = Fimg[pos_f];
      m[c] = sqrtf(v.x * v.x + v.y * v.y);
    } else {
      m[c] = ((const float*)Fimg)[pos_f];
    }
  }
  float l0 = b2[0], l1 = b2[1], l2 = b2[2];
#pragma unroll 4
  for (int k = 0; k < 64; ++k) {
    float acc = b1[k];
#pragma unroll
    for (int c = 0; c < 64; ++c) acc = fmaf(w1[(k << 6) + c], m[c], acc);
    float hv = fmaxf(acc, 0.0f);
    l0 = fmaf(w2[k], hv, l0);          // w2 layout [S=3][HID=64]
    l1 = fmaf(w2[64 + k], hv, l1);
    l2 = fmaf(w2[128 + k], hv, l2);
  }
  float mx = fmaxf(l0, fmaxf(l1, l2));
  float e0 = expf(l0 - mx), e1 = expf(l1 - mx), e2 = expf(l2 - mx);
  float inv = 1.0f / (e0 + e1 + e2);
  float aw0 = e0 * inv, aw1 = e1 * inv, aw2 = e2 * inv;
  // log-Gabor filters on the raw (h,w) grid
  const float yy = -1.0f + (float)h * (2.0f / 63.0f);
  const float xx = -1.0f + (float)w * (2.0f / 63.0f);
  const float r = sqrtf(xx * xx + yy * yy + 1e-6f);
  const float lr = logf(r);
  const float phi = atan2f(yy, xx);
  float wc = 0.0f;
  const float aws[3] = {aw0, aw1, aw2};
#pragma unroll
  for (int s = 0; s < 3; ++s) {
    const float f0v = f0[s * 64 + i];       // [S][O=1][I]
    const float sgv = sigma[s * 64 + i];
    const float thv = theta[s * 64 + i];
    const float t0v = theta0[s * 64 + i];
    const float ls = logf(sgv);
    const float d1 = lr - logf(f0v);
    const float g1 = expf(-(d1 * d1) / (2.0f * ls * ls));
    const float d2 = phi - thv;
    const float g2 = expf(-(d2 * d2) / (2.0f * t0v * t0v));
    wc = fmaf(g1 * g2, aws[s], wc);
  }
  Wc[((i << 6) + h) * 64 + w] = wc;
}

// ---------------------------------------------------------------------------
// K3: spatial 3x3 conv, Cout=1. One WAVE per output row (b,row); lane = w.
// Per channel: 3 coalesced global loads + 9 FMAs into row partials; the w+-1
// neighbor terms assembled once at the end via 2 lane shuffles with boundary
// masks folded in the epilogue. Tiny LDS (weights only) -> high occupancy.
// ---------------------------------------------------------------------------
__global__ __launch_bounds__(256) void k_conv(const float* __restrict__ x,
                                              const float* __restrict__ cw,
                                              float* __restrict__ xsp) {
  __shared__ float wsm[576];
  const int t = threadIdx.x;
  for (int q = t; q < 576; q += 256) wsm[q] = cw[q];
  __syncthreads();
  const int lane = t & 63;
  const int wv = t >> 6;
  const int b = blockIdx.x >> 4;
  const int row = ((blockIdx.x & 15) << 2) | wv;
  const float* xb = x + ((size_t)b << 18);
  const int rm = row > 0 ? row - 1 : 0;    // clamped (masked in epilogue)
  const int rp = row < 63 ? row + 1 : 63;
  float P00 = 0.f, P01 = 0.f, P02 = 0.f;
  float P10 = 0.f, P11 = 0.f, P12 = 0.f;
  float P20 = 0.f, P21 = 0.f, P22 = 0.f;
#pragma unroll 4
  for (int ch = 0; ch < 64; ++ch) {
    const float* xc = xb + (ch << 12);
    const float v0 = xc[(rm << 6) + lane];
    const float v1 = xc[(row << 6) + lane];
    const float v2 = xc[(rp << 6) + lane];
    const float* wp = &wsm[ch * 9];
    P00 = fmaf(v0, wp[0], P00);
    P01 = fmaf(v0, wp[1], P01);
    P02 = fmaf(v0, wp[2], P02);
    P10 = fmaf(v1, wp[3], P10);
    P11 = fmaf(v1, wp[4], P11);
    P12 = fmaf(v1, wp[5], P12);
    P20 = fmaf(v2, wp[6], P20);
    P21 = fmaf(v2, wp[7], P21);
    P22 = fmaf(v2, wp[8], P22);
  }
  const float tmask = (row > 0) ? 1.0f : 0.0f;
  const float bmask = (row < 63) ? 1.0f : 0.0f;
  const float Ql = tmask * P00 + P10 + bmask * P20;
  const float Qm = tmask * P01 + P11 + bmask * P21;
  const float Qr = tmask * P02 + P12 + bmask * P22;
  const float fromL = __shfl_up(Ql, 1, 64);
  const float fromR = __shfl_down(Qr, 1, 64);
  float acc = Qm;
  if (lane > 0) acc += fromL;
  if (lane < 63) acc += fromR;
  xsp[((size_t)b << 12) + (row << 6) + lane] = acc;
}

// ---------------------------------------------------------------------------
// K4: G[b,i,u,v] = F[b,i,u,v]*Wc[i+,u+,v+]*mask(b+,i+,u+); IFFT2; real part;
// mix with conv path. Images with chanmask==0 (~92%) skip the IFFT entirely
// (their F slot holds magnitudes, never read here). LDS stride 65.
// ---------------------------------------------------------------------------
__global__ __launch_bounds__(64) void k_ifft_out(
    const float2* __restrict__ F, const float* __restrict__ Wc,
    const float* __restrict__ xsp, const int* __restrict__ idx,
    const float* __restrict__ mixp, float* __restrict__ out,
    const float* __restrict__ twg) {
  __shared__ float lre[64][65];
  __shared__ float lim[64][65];
  __shared__ float twr[64], twi[64];
  const int t = threadIdx.x;
  const int img = blockIdx.x;
  const int b = img >> 6, i = img & 63;
  const int b_s = (b + 32) & 63, i_s = (i + 32) & 63;
  const int s0 = idx[b_s], e0 = idx[64 + b_s];
  const float mixv = mixp[0];
  float* op = out + ((size_t)img << 12);
  const float* xp = xsp + ((size_t)b << 12);
  if (!((i_s >= s0) && (i_s < e0))) {  // block-uniform: x_filtered == 0
    const float om = 1.0f - mixv;
#pragma unroll
    for (int k = 0; k < 64; ++k) op[k * 64 + t] = om * xp[k * 64 + t];
    return;
  }
  twr[t] = twg[128 + t];
  twi[t] = twg[192 + t];
  const float2* Fp = F + ((size_t)img << 12);
  const float* Wcp = Wc + ((size_t)i_s << 12);
  const int v_s = (t + 32) & 63;
#pragma unroll
  for (int k = 0; k < 64; ++k) {
    const int u_s = (k + 32) & 63;
    float wv = 0.0f;
    if (u_s >= s0 && u_s < e0) wv = Wcp[(u_s << 6) + v_s];
    float2 f = Fp[k * 64 + t];
    lre[k][t] = f.x * wv;
    lim[k][t] = f.y * wv;
  }
  __syncthreads();
  {  // row inverse FFTs
    float re[64], im[64];
#pragma unroll
    for (int j = 0; j < 64; ++j) { re[j] = lre[t][j]; im[j] = lim[t][j]; }
    fft64_regs(re, im, twr, twi);
#pragma unroll
    for (int j = 0; j < 64; ++j) { lre[t][j] = re[j]; lim[t][j] = im[j]; }
  }
  __syncthreads();
  {  // column inverse FFTs
    float re[64], im[64];
#pragma unroll
    for (int j = 0; j < 64; ++j) { re[j] = lre[j][t]; im[j] = lim[j][t]; }
    fft64_regs(re, im, twr, twi);
#pragma unroll
    for (int j = 0; j < 64; ++j) { lre[j][t] = re[j]; lim[j][t] = im[j]; }
  }
  __syncthreads();
  const float sc = mixv * (1.0f / 4096.0f);
  const float om = 1.0f - mixv;
#pragma unroll
  for (int k = 0; k < 64; ++k)
    op[k * 64 + t] = fmaf(sc, lre[k][t], om * xp[k * 64 + t]);
}

// ---------------------------------------------------------------------------
// Workspace layout (needs ~136.3 MB):
//   [0, 128MB)              F        float2[4096*4096] (inactive imgs: |F| fp32)
//   [+0MB, +1MB)            Wc       float[64*64*64]
//   [+1MB, +2MB)            xsp      float[64*64*64]
//   [+2MB, +2MB+1KB)        tw       float[256]
//   [+2MB+1KB, ...)         idx      int[128]
// ---------------------------------------------------------------------------
extern "C" void kernel_launch(void* const* d_in, const int* in_sizes, int n_in,
                              void* d_out, int out_size, void* d_ws, size_t ws_size,
                              hipStream_t stream) {
  const float* x      = (const float*)d_in[0];
  const float* f0     = (const float*)d_in[1];
  const float* theta  = (const float*)d_in[2];
  const float* sigma  = (const float*)d_in[3];
  const float* theta0 = (const float*)d_in[4];
  const float* fbs    = (const float*)d_in[5];
  const float* mix    = (const float*)d_in[6];
  const float* w1     = (const float*)d_in[7];
  const float* b1     = (const float*)d_in[8];
  const float* w2     = (const float*)d_in[9];
  const float* b2     = (const float*)d_in[10];
  const float* cw     = (const float*)d_in[11];
  float* out = (float*)d_out;
  char* ws = (char*)d_ws;
  float2* F  = (float2*)(ws);
  float* Wc  = (float*)(ws + 134217728);
  float* xsp = (float*)(ws + 134217728 + 1048576);
  float* tw  = (float*)(ws + 134217728 + 2097152);
  int* idx   = (int*)(ws + 134217728 + 2097152 + 1024);

  k_setup<<<1, 64, 0, stream>>>(fbs, tw, idx);
  k_fft_fwd<<<4096, 64, 0, stream>>>(x, F, tw, idx);
  k_attn<<<1024, 256, 0, stream>>>(F, w1, b1, w2, b2, f0, theta, sigma, theta0, idx, Wc);
  k_conv<<<1024, 256, 0, stream>>>(x, cw, xsp);
  k_ifft_out<<<4096, 64, 0, stream>>>(F, Wc, xsp, idx, mix, out, tw);
}